// Round 2
// baseline (156.053 us; speedup 1.0000x reference)
//
#include <hip/hip_runtime.h>
#include <hip/hip_bf16.h>
#include <cstdint>

typedef unsigned short u16;
typedef __bf16 bf16_t;
typedef __bf16 bf16x8 __attribute__((ext_vector_type(8)));
typedef float f32x4 __attribute__((ext_vector_type(4)));

#define DM   512
#define DFF  2048
#define NEXP 8

__device__ __forceinline__ u16 f2bf(float f) {
  bf16_t b = (bf16_t)f;
  return __builtin_bit_cast(u16, b);
}
__device__ __forceinline__ uint32_t pack_bf2(float lo, float hi) {
  return (uint32_t)f2bf(lo) | ((uint32_t)f2bf(hi) << 16);
}
__device__ __forceinline__ float gelu_tanh(float x) {
  float x3 = x * x * x;
  float z = 0.7978845608028654f * (x + 0.044715f * x3);
  float az = fabsf(z);
  float e = __expf(2.0f * az);
  float t = 1.0f - 2.0f / (e + 1.0f);
  t = copysignf(t, z);
  return 0.5f * x * (1.0f + t);
}
__device__ __forceinline__ void async16(const u16* g, u16* l) {
  __builtin_amdgcn_global_load_lds((const __attribute__((address_space(1))) void*)g,
                                   (__attribute__((address_space(3))) void*)l, 16, 0, 0);
}

// ---------- transpose + f32->bf16 convert: src [E][R][C] f32 -> dst [E][C][R] bf16
__global__ void k_transpose_cvt(const float* __restrict__ src, u16* __restrict__ dst,
                                int R, int C) {
  __shared__ u16 tile[64][66];   // pad 66: u32-aligned rows, 2-way col-read conflicts only
  int e = blockIdx.y;
  int tilesC = C >> 6;
  int bR = (blockIdx.x / tilesC) << 6;
  int bC = (blockIdx.x % tilesC) << 6;
  const float* s = src + (size_t)e * R * C;
  u16* d = dst + (size_t)e * R * C;
  int rr = threadIdx.x >> 4;          // 0..15
  int cc = (threadIdx.x & 15) << 2;   // 0..60 step 4
#pragma unroll
  for (int i = 0; i < 4; ++i) {
    int r = (i << 4) + rr;
    float4 v = *(const float4*)(s + (size_t)(bR + r) * C + bC + cc);
    *(uint32_t*)&tile[r][cc]     = pack_bf2(v.x, v.y);
    *(uint32_t*)&tile[r][cc + 2] = pack_bf2(v.z, v.w);
  }
  __syncthreads();
  int c0 = threadIdx.x >> 5;          // 0..7
  int j  = (threadIdx.x & 31) << 1;   // 0..62 step 2
#pragma unroll
  for (int i = 0; i < 8; ++i) {
    int c = (i << 3) + c0;
    uint32_t v = (uint32_t)tile[j][c] | ((uint32_t)tile[j + 1][c] << 16);
    *(uint32_t*)(&d[(size_t)(bC + c) * R + bR + j]) = v;
  }
}

// ---------- router: one wave per token
__global__ void k_router(const float* __restrict__ x, const float* __restrict__ Wr,
                         const float* __restrict__ br, int* __restrict__ sel_idx,
                         float* __restrict__ sel_w, int Ntok) {
  int wid = threadIdx.x >> 6;
  int lane = threadIdx.x & 63;
  int tok = (blockIdx.x << 2) + wid;
  if (tok >= Ntok) return;
  const float4* xr = (const float4*)(x + (size_t)tok * DM);
  float4 x0 = xr[lane * 2], x1 = xr[lane * 2 + 1];
  float logit[NEXP];
#pragma unroll
  for (int e = 0; e < NEXP; ++e) {
    const float4* wr = (const float4*)(Wr + e * DM);
    float4 w0 = wr[lane * 2], w1 = wr[lane * 2 + 1];
    float p = x0.x * w0.x + x0.y * w0.y + x0.z * w0.z + x0.w * w0.w
            + x1.x * w1.x + x1.y * w1.y + x1.z * w1.z + x1.w * w1.w;
#pragma unroll
    for (int off = 32; off; off >>= 1) p += __shfl_xor(p, off, 64);
    logit[e] = p + br[e];
  }
  if (lane == 0) {
    float mx = logit[0];
#pragma unroll
    for (int e = 1; e < NEXP; ++e) mx = fmaxf(mx, logit[e]);
    float pr[NEXP];
#pragma unroll
    for (int e = 0; e < NEXP; ++e) pr[e] = __expf(logit[e] - mx);
    int i0 = 0;
#pragma unroll
    for (int e = 1; e < NEXP; ++e) if (pr[e] > pr[i0]) i0 = e;
    int i1 = -1;
#pragma unroll
    for (int e = 0; e < NEXP; ++e) {
      if (e == i0) continue;
      if (i1 < 0 || pr[e] > pr[i1]) i1 = e;
    }
    float s2 = pr[i0] + pr[i1];
    sel_idx[tok * 2]     = i0;
    sel_idx[tok * 2 + 1] = i1;
    sel_w[tok * 2]       = pr[i0] / s2;
    sel_w[tok * 2 + 1]   = pr[i1] / s2;
  }
}

// ---------- scatter: ballot-based histogram + offsets + tile map + positions (1 block)
// NOTE: npairs must be a multiple of blockDim (8192 % 1024 == 0) so ballots are full-wave.
__global__ void k_scatter(const int* __restrict__ sel_idx, const float* __restrict__ sel_w,
                          int npairs, int* __restrict__ row_token, float* __restrict__ row_w,
                          int* __restrict__ pos_of, int* __restrict__ tileMeta,
                          int* __restrict__ gMeta) {
  __shared__ int cnt[NEXP], offs[NEXP], cur[NEXP];
  int tid = threadIdx.x;
  int lane = tid & 63;
  if (tid < NEXP) { cnt[tid] = 0; cur[tid] = 0; }
  __syncthreads();
  for (int p = tid; p < npairs; p += blockDim.x) {
    int e = sel_idx[p];
#pragma unroll
    for (int ex = 0; ex < NEXP; ++ex) {
      unsigned long long m = __ballot(e == ex);
      if (lane == 0 && m) atomicAdd(&cnt[ex], __popcll(m));
    }
  }
  __syncthreads();
  if (tid == 0) {
    int o = 0, nmt = 0;
    for (int e = 0; e < NEXP; ++e) {
      offs[e] = o;
      int c = cnt[e];
      int nt = (c + 127) >> 7;
      for (int t = 0; t < nt; ++t) {
        tileMeta[nmt * 3 + 0] = o + t * 128;  // posStart
        tileMeta[nmt * 3 + 1] = o + c;        // segEnd
        tileMeta[nmt * 3 + 2] = e;            // expert
        ++nmt;
      }
      o += c;
    }
    gMeta[0] = nmt;
  }
  __syncthreads();
  for (int p = tid; p < npairs; p += blockDim.x) {
    int e = sel_idx[p];
    int pos = 0;
#pragma unroll
    for (int ex = 0; ex < NEXP; ++ex) {
      unsigned long long m = __ballot(e == ex);
      if (m) {
        int leader = __ffsll((long long)m) - 1;
        int base = 0;
        if (lane == leader) base = atomicAdd(&cur[ex], __popcll(m));
        base = __shfl(base, leader, 64);
        if (e == ex)
          pos = offs[ex] + base + __popcll(m & ((1ull << lane) - 1ull));
      }
    }
    row_token[pos] = p >> 1;
    row_w[pos] = sel_w[p];
    pos_of[p] = pos;
  }
}

// ---------- gather selected token rows -> bf16
__global__ void k_gather(const float* __restrict__ x, const int* __restrict__ row_token,
                         u16* __restrict__ Xg, int npairs) {
  int pos = (blockIdx.x << 2) + (threadIdx.x >> 6);
  int lane = threadIdx.x & 63;
  if (pos >= npairs) return;
  int tok = row_token[pos];
  const float4* src = (const float4*)(x + (size_t)tok * DM);
  float4 a = src[lane * 2], b = src[lane * 2 + 1];
  uint4 o;
  o.x = pack_bf2(a.x, a.y);
  o.y = pack_bf2(a.z, a.w);
  o.z = pack_bf2(b.x, b.y);
  o.w = pack_bf2(b.z, b.w);
  ((uint4*)(Xg + (size_t)pos * DM))[lane] = o;
}

// ---------- grouped GEMM: C[m][n] = act(A[m][:] . BT[n][:] + bias) (*w), bf16 out
// A: [npairs][K] bf16   BT: [E][NFULL][K] bf16   out: bf16 [npairs][NFULL]
// Double-buffered: STAGE(next) issued before compute(cur); one barrier/K-tile.
template <int NFULL, int K, bool GELU, bool SCALE>
__launch_bounds__(256)
__global__ void k_gemm(const u16* __restrict__ A, const u16* __restrict__ BT,
                       const float* __restrict__ bias, const float* __restrict__ row_w,
                       u16* __restrict__ Out, const int* __restrict__ tileMeta,
                       const int* __restrict__ gMeta) {
  int mt = blockIdx.x;
  if (mt >= gMeta[0]) return;
  int nt = blockIdx.y;
  int posStart = tileMeta[mt * 3 + 0];
  int segEnd   = tileMeta[mt * 3 + 1];
  int e        = tileMeta[mt * 3 + 2];

  // smem: As0 | Bs0 | As1 | Bs1, each 128x64 u16 (16KB) -> 64KB total
  __shared__ u16 smem[32768];

  int tid = threadIdx.x;
  int lane = tid & 63, wid = tid >> 6;
  int wm = wid >> 1, wn = wid & 1;

  const u16* Bex = BT + ((size_t)e * NFULL + (size_t)nt * 128) * K;

  // staging source pointers (pre-swizzled global source, linear LDS dest)
  int sRow = (wid << 3) + (lane >> 3);   // +i*32
  int chunkDst = lane & 7;
  const u16* aSrc[4];
  const u16* bSrc[4];
#pragma unroll
  for (int i = 0; i < 4; ++i) {
    int r = (i << 5) + sRow;
    int gra = posStart + r;
    if (gra >= segEnd) gra = segEnd - 1;
    int cs = chunkDst ^ (r & 7);
    aSrc[i] = A + (size_t)gra * K + cs * 8;
    bSrc[i] = Bex + (size_t)r * K + cs * 8;
  }

  auto stage = [&](int kt, int buf) {
    u16* as = smem + (buf << 14);
    u16* bs = as + 8192;
#pragma unroll
    for (int i = 0; i < 4; ++i) {
      async16(aSrc[i] + kt * 64, as + (i << 11) + (wid << 9));
      async16(bSrc[i] + kt * 64, bs + (i << 11) + (wid << 9));
    }
  };

  f32x4 acc[4][4] = {};
  constexpr int NK = K / 64;

  stage(0, 0);
  __syncthreads();   // drains vmcnt(0): buf0 ready

  for (int kt = 0; kt < NK; ++kt) {
    int cur = kt & 1;
    if (kt + 1 < NK) stage(kt + 1, cur ^ 1);   // async: flies during compute
    const char* AsB = (const char*)(smem + (cur << 14));
    const char* BsB = AsB + 16384;
#pragma unroll
    for (int ks = 0; ks < 2; ++ks) {
      int kByte = (ks << 6) + ((lane >> 4) << 4);
      bf16x8 av[4], bv[4];
#pragma unroll
      for (int mi = 0; mi < 4; ++mi) {
        int row = (wm << 6) + (mi << 4) + (lane & 15);
        av[mi] = *(const bf16x8*)(AsB + row * 128 + (kByte ^ ((row & 7) << 4)));
      }
#pragma unroll
      for (int ni = 0; ni < 4; ++ni) {
        int row = (wn << 6) + (ni << 4) + (lane & 15);
        bv[ni] = *(const bf16x8*)(BsB + row * 128 + (kByte ^ ((row & 7) << 4)));
      }
#pragma unroll
      for (int mi = 0; mi < 4; ++mi)
#pragma unroll
        for (int ni = 0; ni < 4; ++ni)
          acc[mi][ni] = __builtin_amdgcn_mfma_f32_16x16x32_bf16(av[mi], bv[ni], acc[mi][ni], 0, 0, 0);
    }
    __syncthreads();   // drains vmcnt(0) -> next buf ready; protects buf reuse
  }

  // epilogue: frag -> LDS (pad 132, conflict-balanced) -> coalesced 16B stores
  u16* Cs = smem;   // 128 x 132 u16 = 33KB, fits; all compute done (loop ends with barrier)
  int laneCol = lane & 15;
  int laneRow4 = (lane >> 4) << 2;
  const float* biasE = bias + (size_t)e * NFULL;
#pragma unroll
  for (int mi = 0; mi < 4; ++mi) {
#pragma unroll
    for (int j = 0; j < 4; ++j) {
      int r = (wm << 6) + (mi << 4) + laneRow4 + j;
      int m = posStart + r;
      float w = 1.0f;
      if constexpr (SCALE) w = row_w[m < segEnd ? m : posStart];
#pragma unroll
      for (int ni = 0; ni < 4; ++ni) {
        int cl = (wn << 6) + (ni << 4) + laneCol;
        float v = acc[mi][ni][j] + biasE[(nt << 7) + cl];
        if constexpr (GELU) v = gelu_tanh(v);
        if constexpr (SCALE) v *= w;
        Cs[r * 132 + cl] = f2bf(v);
      }
    }
  }
  __syncthreads();
  int r0 = tid >> 4;       // 0..15
  int q  = tid & 15;       // uint4 index within 256B row
  uint4* outBase = (uint4*)(Out + (size_t)posStart * NFULL + (nt << 7));
#pragma unroll
  for (int i = 0; i < 8; ++i) {
    int r = (i << 4) + r0;
    if (posStart + r < segEnd)
      *((uint4*)(Out + (size_t)(posStart + r) * NFULL + (nt << 7)) + q) =
          ((uint4*)(Cs + r * 132))[q];
  }
  (void)outBase;
}

// ---------- combine: out[tok] = Ys[pos0] + Ys[pos1]   (w and b2 already applied), Ys bf16
__global__ void k_combine(const u16* __restrict__ Ys, const int* __restrict__ pos_of,
                          float* __restrict__ out, int Ntok) {
  int tok = (blockIdx.x << 2) + (threadIdx.x >> 6);
  int lane = threadIdx.x & 63;
  if (tok >= Ntok) return;
  int p0 = pos_of[tok * 2], p1 = pos_of[tok * 2 + 1];
  bf16x8 a = ((const bf16x8*)(Ys + (size_t)p0 * DM))[lane];
  bf16x8 b = ((const bf16x8*)(Ys + (size_t)p1 * DM))[lane];
  float4 o0, o1;
  o0.x = (float)a[0] + (float)b[0];
  o0.y = (float)a[1] + (float)b[1];
  o0.z = (float)a[2] + (float)b[2];
  o0.w = (float)a[3] + (float)b[3];
  o1.x = (float)a[4] + (float)b[4];
  o1.y = (float)a[5] + (float)b[5];
  o1.z = (float)a[6] + (float)b[6];
  o1.w = (float)a[7] + (float)b[7];
  float4* o = (float4*)(out + (size_t)tok * DM + lane * 8);
  o[0] = o0;
  o[1] = o1;
}

extern "C" void kernel_launch(void* const* d_in, const int* in_sizes, int n_in,
                              void* d_out, int out_size, void* d_ws, size_t ws_size,
                              hipStream_t stream) {
  const float* x  = (const float*)d_in[0];
  const float* Wr = (const float*)d_in[1];
  const float* br = (const float*)d_in[2];
  const float* W1 = (const float*)d_in[3];
  const float* b1 = (const float*)d_in[4];
  const float* W2 = (const float*)d_in[5];
  const float* b2 = (const float*)d_in[6];
  float* out = (float*)d_out;

  int Ntok = in_sizes[0] / DM;   // 4096
  int npairs = Ntok * 2;         // 8192
  int maxmt = npairs / 128 + NEXP;

  char* p = (char*)d_ws;
  u16* W1T = (u16*)p;  p += (size_t)NEXP * DFF * DM * 2;
  u16* W2T = (u16*)p;  p += (size_t)NEXP * DM * DFF * 2;
  u16* Xg  = (u16*)p;  p += (size_t)npairs * DM * 2;
  u16* H   = (u16*)p;  p += (size_t)npairs * DFF * 2;
  u16* Ys  = (u16*)p;  p += (size_t)npairs * DM * 2;
  int* sel_idx   = (int*)p;   p += (size_t)npairs * 4;
  float* sel_w   = (float*)p; p += (size_t)npairs * 4;
  int* pos_of    = (int*)p;   p += (size_t)npairs * 4;
  int* row_token = (int*)p;   p += (size_t)npairs * 4;
  float* row_w   = (float*)p; p += (size_t)npairs * 4;
  int* tileMeta  = (int*)p;   p += (size_t)(maxmt * 3 + 16) * 4;
  int* gMeta     = (int*)p;   p += 64;

  k_transpose_cvt<<<dim3((DM / 64) * (DFF / 64), NEXP), 256, 0, stream>>>(W1, W1T, DM, DFF);
  k_transpose_cvt<<<dim3((DFF / 64) * (DM / 64), NEXP), 256, 0, stream>>>(W2, W2T, DFF, DM);
  k_router<<<dim3((Ntok + 3) / 4), 256, 0, stream>>>(x, Wr, br, sel_idx, sel_w, Ntok);
  k_scatter<<<dim3(1), 1024, 0, stream>>>(sel_idx, sel_w, npairs, row_token, row_w,
                                          pos_of, tileMeta, gMeta);
  k_gather<<<dim3(npairs / 4), 256, 0, stream>>>(x, row_token, Xg, npairs);
  k_gemm<DFF, DM, true, false>
      <<<dim3(maxmt, DFF / 128), 256, 0, stream>>>(Xg, W1T, b1, nullptr, H, tileMeta, gMeta);
  k_gemm<DM, DFF, false, true>
      <<<dim3(maxmt, DM / 128), 256, 0, stream>>>(H, W2T, b2, row_w, Ys, tileMeta, gMeta);
  k_combine<<<dim3(Ntok / 4), 256, 0, stream>>>(Ys, pos_of, out, Ntok);
}

// Round 3
// 144.419 us; speedup vs baseline: 1.0806x; 1.0806x over previous
//
#include <hip/hip_runtime.h>
#include <hip/hip_bf16.h>
#include <cstdint>

typedef unsigned short u16;
typedef __bf16 bf16_t;
typedef __bf16 bf16x8 __attribute__((ext_vector_type(8)));
typedef float f32x4 __attribute__((ext_vector_type(4)));

#define DM   512
#define DFF  2048
#define NEXP 8

__device__ __forceinline__ u16 f2bf(float f) {
  bf16_t b = (bf16_t)f;
  return __builtin_bit_cast(u16, b);
}
__device__ __forceinline__ uint32_t pack_bf2(float lo, float hi) {
  return (uint32_t)f2bf(lo) | ((uint32_t)f2bf(hi) << 16);
}
__device__ __forceinline__ float gelu_tanh(float x) {
  float x3 = x * x * x;
  float z = 0.7978845608028654f * (x + 0.044715f * x3);
  float az = fabsf(z);
  float e = __expf(2.0f * az);
  float t = 1.0f - 2.0f / (e + 1.0f);
  t = copysignf(t, z);
  return 0.5f * x * (1.0f + t);
}
__device__ __forceinline__ void async16(const u16* g, u16* l) {
  __builtin_amdgcn_global_load_lds((const __attribute__((address_space(1))) void*)g,
                                   (__attribute__((address_space(3))) void*)l, 16, 0, 0);
}

// ---------- transpose + f32->bf16 convert: src [E][R][C] f32 -> dst [E][C][R] bf16
__global__ void k_transpose_cvt(const float* __restrict__ src, u16* __restrict__ dst,
                                int R, int C) {
  __shared__ u16 tile[64][66];
  int e = blockIdx.y;
  int tilesC = C >> 6;
  int bR = (blockIdx.x / tilesC) << 6;
  int bC = (blockIdx.x % tilesC) << 6;
  const float* s = src + (size_t)e * R * C;
  u16* d = dst + (size_t)e * R * C;
  int rr = threadIdx.x >> 4;
  int cc = (threadIdx.x & 15) << 2;
#pragma unroll
  for (int i = 0; i < 4; ++i) {
    int r = (i << 4) + rr;
    float4 v = *(const float4*)(s + (size_t)(bR + r) * C + bC + cc);
    *(uint32_t*)&tile[r][cc]     = pack_bf2(v.x, v.y);
    *(uint32_t*)&tile[r][cc + 2] = pack_bf2(v.z, v.w);
  }
  __syncthreads();
  int c0 = threadIdx.x >> 5;
  int j  = (threadIdx.x & 31) << 1;
#pragma unroll
  for (int i = 0; i < 8; ++i) {
    int c = (i << 3) + c0;
    uint32_t v = (uint32_t)tile[j][c] | ((uint32_t)tile[j + 1][c] << 16);
    *(uint32_t*)(&d[(size_t)(bC + c) * R + bR + j]) = v;
  }
}

// ---------- router: one wave per token
__global__ void k_router(const float* __restrict__ x, const float* __restrict__ Wr,
                         const float* __restrict__ br, int* __restrict__ sel_idx,
                         float* __restrict__ sel_w, int Ntok) {
  int wid = threadIdx.x >> 6;
  int lane = threadIdx.x & 63;
  int tok = (blockIdx.x << 2) + wid;
  if (tok >= Ntok) return;
  const float4* xr = (const float4*)(x + (size_t)tok * DM);
  float4 x0 = xr[lane * 2], x1 = xr[lane * 2 + 1];
  float logit[NEXP];
#pragma unroll
  for (int e = 0; e < NEXP; ++e) {
    const float4* wr = (const float4*)(Wr + e * DM);
    float4 w0 = wr[lane * 2], w1 = wr[lane * 2 + 1];
    float p = x0.x * w0.x + x0.y * w0.y + x0.z * w0.z + x0.w * w0.w
            + x1.x * w1.x + x1.y * w1.y + x1.z * w1.z + x1.w * w1.w;
#pragma unroll
    for (int off = 32; off; off >>= 1) p += __shfl_xor(p, off, 64);
    logit[e] = p + br[e];
  }
  if (lane == 0) {
    float mx = logit[0];
#pragma unroll
    for (int e = 1; e < NEXP; ++e) mx = fmaxf(mx, logit[e]);
    float pr[NEXP];
#pragma unroll
    for (int e = 0; e < NEXP; ++e) pr[e] = __expf(logit[e] - mx);
    int i0 = 0;
#pragma unroll
    for (int e = 1; e < NEXP; ++e) if (pr[e] > pr[i0]) i0 = e;
    int i1 = -1;
#pragma unroll
    for (int e = 0; e < NEXP; ++e) {
      if (e == i0) continue;
      if (i1 < 0 || pr[e] > pr[i1]) i1 = e;
    }
    float s2 = pr[i0] + pr[i1];
    sel_idx[tok * 2]     = i0;
    sel_idx[tok * 2 + 1] = i1;
    sel_w[tok * 2]       = pr[i0] / s2;
    sel_w[tok * 2 + 1]   = pr[i1] / s2;
  }
}

// ---------- scatter (1 block, ballot-based)
__global__ void k_scatter(const int* __restrict__ sel_idx, const float* __restrict__ sel_w,
                          int npairs, int* __restrict__ row_token, float* __restrict__ row_w,
                          int* __restrict__ pos_of, int* __restrict__ tileMeta,
                          int* __restrict__ gMeta) {
  __shared__ int cnt[NEXP], offs[NEXP], cur[NEXP];
  int tid = threadIdx.x;
  int lane = tid & 63;
  if (tid < NEXP) { cnt[tid] = 0; cur[tid] = 0; }
  __syncthreads();
  for (int p = tid; p < npairs; p += blockDim.x) {
    int e = sel_idx[p];
#pragma unroll
    for (int ex = 0; ex < NEXP; ++ex) {
      unsigned long long m = __ballot(e == ex);
      if (lane == 0 && m) atomicAdd(&cnt[ex], __popcll(m));
    }
  }
  __syncthreads();
  if (tid == 0) {
    int o = 0, nmt = 0;
    for (int e = 0; e < NEXP; ++e) {
      offs[e] = o;
      int c = cnt[e];
      int nt = (c + 127) >> 7;
      for (int t = 0; t < nt; ++t) {
        tileMeta[nmt * 3 + 0] = o + t * 128;
        tileMeta[nmt * 3 + 1] = o + c;
        tileMeta[nmt * 3 + 2] = e;
        ++nmt;
      }
      o += c;
    }
    gMeta[0] = nmt;
  }
  __syncthreads();
  for (int p = tid; p < npairs; p += blockDim.x) {
    int e = sel_idx[p];
    int pos = 0;
#pragma unroll
    for (int ex = 0; ex < NEXP; ++ex) {
      unsigned long long m = __ballot(e == ex);
      if (m) {
        int leader = __ffsll((long long)m) - 1;
        int base = 0;
        if (lane == leader) base = atomicAdd(&cur[ex], __popcll(m));
        base = __shfl(base, leader, 64);
        if (e == ex)
          pos = offs[ex] + base + __popcll(m & ((1ull << lane) - 1ull));
      }
    }
    row_token[pos] = p >> 1;
    row_w[pos] = sel_w[p];
    pos_of[p] = pos;
  }
}

// ---------- gather selected token rows -> bf16
__global__ void k_gather(const float* __restrict__ x, const int* __restrict__ row_token,
                         u16* __restrict__ Xg, int npairs) {
  int pos = (blockIdx.x << 2) + (threadIdx.x >> 6);
  int lane = threadIdx.x & 63;
  if (pos >= npairs) return;
  int tok = row_token[pos];
  const float4* src = (const float4*)(x + (size_t)tok * DM);
  float4 a = src[lane * 2], b = src[lane * 2 + 1];
  uint4 o;
  o.x = pack_bf2(a.x, a.y);
  o.y = pack_bf2(a.z, a.w);
  o.z = pack_bf2(b.x, b.y);
  o.w = pack_bf2(b.z, b.w);
  ((uint4*)(Xg + (size_t)pos * DM))[lane] = o;
}

// ---------- grouped GEMM, counted-vmcnt triple-buffer pipeline, BK=32
// A: [npairs][KTOT] bf16   BT: [E][NFULL][KTOT] bf16
// OUTBF16: Out = bf16 [npairs][NFULL] (GELU).  else: f32 partial at split*pstride (SCALE).
template <int NFULL, int KTOT, int KCHUNK, bool GELU, bool SCALE, bool OUTBF16>
__launch_bounds__(256)
__global__ void k_gemm(const u16* __restrict__ A, const u16* __restrict__ BT,
                       const float* __restrict__ bias, const float* __restrict__ row_w,
                       void* __restrict__ Out, size_t pstride,
                       const int* __restrict__ tileMeta, const int* __restrict__ gMeta,
                       int maxmt) {
  constexpr int NT = NFULL / 128;
  constexpr int NK = KCHUNK / 32;
  int NB = gridDim.x;
  int bid = blockIdx.x;
  int wg = ((NB & 7) == 0) ? ((bid & 7) * (NB >> 3) + (bid >> 3)) : bid;  // XCD chunking
  int nt = wg % NT;                      // nt fastest -> A-tile L2 reuse within XCD
  int rem = wg / NT;
  int mt = rem % maxmt;
  int split = rem / maxmt;
  if (mt >= gMeta[0]) return;
  int posStart = tileMeta[mt * 3 + 0];
  int segEnd   = tileMeta[mt * 3 + 1];
  int e        = tileMeta[mt * 3 + 2];

  // 3 buffers x (A 128x32 + B 128x32) u16 = 3 x 16KB = 48KB
  __shared__ __align__(16) u16 smem[24576];

  int tid = threadIdx.x, lane = tid & 63, wid = tid >> 6;
  int wm = wid >> 1, wn = wid & 1;

  const u16* Abase = A + (size_t)split * KCHUNK;
  const u16* Bbase = BT + ((size_t)e * NFULL + (size_t)nt * 128) * KTOT + (size_t)split * KCHUNK;

  // staging: wave w instr i covers tile rows [i*64 + w*16, +16), 64B/row, linear LDS dest.
  // global source pre-swizzled: chunk cs = c4 ^ ((row>>1)&3)  (2-way max on read = free)
  int l4 = lane >> 2, c4 = lane & 3;
  const u16* aS[2];
  const u16* bS[2];
#pragma unroll
  for (int i = 0; i < 2; ++i) {
    int r = i * 64 + wid * 16 + l4;
    int gra = posStart + r;
    if (gra >= segEnd) gra = segEnd - 1;
    int cs = c4 ^ ((r >> 1) & 3);
    aS[i] = Abase + (size_t)gra * KTOT + cs * 8;
    bS[i] = Bbase + (size_t)r * KTOT + cs * 8;
  }

  auto stage = [&](int kt, int buf) {
    u16* as = smem + buf * 8192;
    u16* bs = as + 4096;
#pragma unroll
    for (int i = 0; i < 2; ++i) {
      async16(aS[i] + kt * 32, as + i * 2048 + wid * 512);
      async16(bS[i] + kt * 32, bs + i * 2048 + wid * 512);
    }
  };

  f32x4 acc[4][4] = {};

  stage(0, 0);
  stage(1, 1);
  int bufC = 0, bufS = 2;
#pragma unroll 1
  for (int t = 0; t < NK; ++t) {
    if (t + 1 < NK) asm volatile("s_waitcnt vmcnt(4)" ::: "memory");
    else            asm volatile("s_waitcnt vmcnt(0)" ::: "memory");
    __builtin_amdgcn_s_barrier();
    asm volatile("" ::: "memory");
    if (t + 2 < NK) { stage(t + 2, bufS); bufS = (bufS == 2) ? 0 : bufS + 1; }
    const char* AsB = (const char*)(smem + bufC * 8192);
    const char* BsB = AsB + 8192;
    int kb = (lane >> 4) << 4;
    bf16x8 av[4], bv[4];
#pragma unroll
    for (int mi = 0; mi < 4; ++mi) {
      int row = (wm << 6) + (mi << 4) + (lane & 15);
      av[mi] = *(const bf16x8*)(AsB + row * 64 + (kb ^ (((row >> 1) & 3) << 4)));
    }
#pragma unroll
    for (int ni = 0; ni < 4; ++ni) {
      int row = (wn << 6) + (ni << 4) + (lane & 15);
      bv[ni] = *(const bf16x8*)(BsB + row * 64 + (kb ^ (((row >> 1) & 3) << 4)));
    }
    __builtin_amdgcn_s_setprio(1);
#pragma unroll
    for (int mi = 0; mi < 4; ++mi)
#pragma unroll
      for (int ni = 0; ni < 4; ++ni)
        acc[mi][ni] = __builtin_amdgcn_mfma_f32_16x16x32_bf16(av[mi], bv[ni], acc[mi][ni], 0, 0, 0);
    __builtin_amdgcn_s_setprio(0);
    bufC = (bufC == 2) ? 0 : bufC + 1;
  }

  int laneCol = lane & 15;
  int laneRow4 = (lane >> 4) << 2;
  const float* biasE = bias + (size_t)e * NFULL;

  if constexpr (OUTBF16) {
    __syncthreads();
    u16* Cs = smem;   // 128 x 136 u16 = 34KB (16B-aligned rows)
#pragma unroll
    for (int mi = 0; mi < 4; ++mi) {
#pragma unroll
      for (int j = 0; j < 4; ++j) {
        int r = (wm << 6) + (mi << 4) + laneRow4 + j;
#pragma unroll
        for (int ni = 0; ni < 4; ++ni) {
          int cl = (wn << 6) + (ni << 4) + laneCol;
          float v = acc[mi][ni][j] + biasE[(nt << 7) + cl];
          if constexpr (GELU) v = gelu_tanh(v);
          Cs[r * 136 + cl] = f2bf(v);
        }
      }
    }
    __syncthreads();
    int r0 = tid >> 4, q = tid & 15;
    u16* OutU = (u16*)Out;
#pragma unroll
    for (int i = 0; i < 8; ++i) {
      int r = (i << 4) + r0;
      if (posStart + r < segEnd)
        *((uint4*)(OutU + (size_t)(posStart + r) * NFULL + (nt << 7)) + q) =
            ((uint4*)(Cs + (size_t)r * 136))[q];
    }
  } else {
    float* OutF = (float*)Out + (size_t)split * pstride;
#pragma unroll
    for (int mi = 0; mi < 4; ++mi) {
#pragma unroll
      for (int j = 0; j < 4; ++j) {
        int m = posStart + (wm << 6) + (mi << 4) + laneRow4 + j;
        if (m < segEnd) {
          float w = 1.0f;
          if constexpr (SCALE) w = row_w[m];
#pragma unroll
          for (int ni = 0; ni < 4; ++ni) {
            int n = (nt << 7) + (wn << 6) + (ni << 4) + laneCol;
            float v = acc[mi][ni][j] + (split == 0 ? biasE[n] : 0.0f);
            OutF[(size_t)m * NFULL + n] = v * w;
          }
        }
      }
    }
  }
}

// ---------- combine: out[tok] = sum over {split0,split1} x {pos0,pos1} of f32 partials
__global__ void k_combine(const float* __restrict__ P, size_t pstride,
                          const int* __restrict__ pos_of, float* __restrict__ out, int Ntok) {
  int tok = (blockIdx.x << 2) + (threadIdx.x >> 6);
  int lane = threadIdx.x & 63;
  if (tok >= Ntok) return;
  int p0 = pos_of[tok * 2], p1 = pos_of[tok * 2 + 1];
  const float4* a0 = (const float4*)(P + (size_t)p0 * DM);
  const float4* a1 = (const float4*)(P + pstride + (size_t)p0 * DM);
  const float4* b0 = (const float4*)(P + (size_t)p1 * DM);
  const float4* b1 = (const float4*)(P + pstride + (size_t)p1 * DM);
  float4* o = (float4*)(out + (size_t)tok * DM);
#pragma unroll
  for (int i = 0; i < 2; ++i) {
    int idx = lane * 2 + i;
    float4 x0 = a0[idx], x1 = a1[idx], y0 = b0[idx], y1 = b1[idx];
    o[idx] = make_float4(x0.x + x1.x + y0.x + y1.x,
                         x0.y + x1.y + y0.y + y1.y,
                         x0.z + x1.z + y0.z + y1.z,
                         x0.w + x1.w + y0.w + y1.w);
  }
}

extern "C" void kernel_launch(void* const* d_in, const int* in_sizes, int n_in,
                              void* d_out, int out_size, void* d_ws, size_t ws_size,
                              hipStream_t stream) {
  const float* x  = (const float*)d_in[0];
  const float* Wr = (const float*)d_in[1];
  const float* br = (const float*)d_in[2];
  const float* W1 = (const float*)d_in[3];
  const float* b1 = (const float*)d_in[4];
  const float* W2 = (const float*)d_in[5];
  const float* b2 = (const float*)d_in[6];
  float* out = (float*)d_out;

  int Ntok = in_sizes[0] / DM;   // 4096
  int npairs = Ntok * 2;         // 8192
  int maxmt = npairs / 128 + NEXP;  // 72
  size_t pstride = (size_t)npairs * DM;

  char* p = (char*)d_ws;
  u16* W1T = (u16*)p;  p += (size_t)NEXP * DFF * DM * 2;
  u16* W2T = (u16*)p;  p += (size_t)NEXP * DM * DFF * 2;
  u16* Xg  = (u16*)p;  p += (size_t)npairs * DM * 2;
  u16* H   = (u16*)p;  p += (size_t)npairs * DFF * 2;
  float* Part = (float*)p; p += 2 * pstride * 4;   // [2][npairs][DM] f32
  int* sel_idx   = (int*)p;   p += (size_t)npairs * 4;
  float* sel_w   = (float*)p; p += (size_t)npairs * 4;
  int* pos_of    = (int*)p;   p += (size_t)npairs * 4;
  int* row_token = (int*)p;   p += (size_t)npairs * 4;
  float* row_w   = (float*)p; p += (size_t)npairs * 4;
  int* tileMeta  = (int*)p;   p += (size_t)(maxmt * 3 + 16) * 4;
  int* gMeta     = (int*)p;   p += 64;

  k_transpose_cvt<<<dim3((DM / 64) * (DFF / 64), NEXP), 256, 0, stream>>>(W1, W1T, DM, DFF);
  k_transpose_cvt<<<dim3((DFF / 64) * (DM / 64), NEXP), 256, 0, stream>>>(W2, W2T, DFF, DM);
  k_router<<<dim3((Ntok + 3) / 4), 256, 0, stream>>>(x, Wr, br, sel_idx, sel_w, Ntok);
  k_scatter<<<dim3(1), 1024, 0, stream>>>(sel_idx, sel_w, npairs, row_token, row_w,
                                          pos_of, tileMeta, gMeta);
  k_gather<<<dim3(npairs / 4), 256, 0, stream>>>(x, row_token, Xg, npairs);
  // GEMM1: [npairs x 2048] = Xg[npairs x 512] * W1T, GELU, bf16 out
  k_gemm<DFF, DM, DM, true, false, true>
      <<<dim3(maxmt * (DFF / 128)), 256, 0, stream>>>(
          Xg, W1T, b1, nullptr, H, 0, tileMeta, gMeta, maxmt);
  // GEMM2: split-K=2, f32 partials, bias on split0, row_w scale
  k_gemm<DM, DFF, DFF / 2, false, true, false>
      <<<dim3(maxmt * (DM / 128) * 2), 256, 0, stream>>>(
          H, W2T, b2, row_w, Part, pstride, tileMeta, gMeta, maxmt);
  k_combine<<<dim3(Ntok / 4), 256, 0, stream>>>(Part, pstride, pos_of, out, Ntok);
}